// Round 13
// baseline (720.547 us; speedup 1.0000x reference)
//
#include <hip/hip_runtime.h>
#include <math.h>

#define B_ 2
#define T_ 512
#define D_ 256
#define NH_ 4
#define NI_ 4096
#define IN_DIM_ 372
#define NL_ 6
#define EPS_ 1e-5f

typedef unsigned short u16;
typedef __attribute__((ext_vector_type(4))) float f32x4;
typedef __attribute__((ext_vector_type(8))) short bf16x8;

__device__ __forceinline__ u16 f2b(float f) {
  union { float f; unsigned u; } v; v.f = f;
  unsigned r = v.u + 0x7fffu + ((v.u >> 16) & 1u);
  return (u16)(r >> 16);
}
__device__ __forceinline__ float b2f(u16 s) {
  union { unsigned u; float f; } v; v.u = ((unsigned)s) << 16;
  return v.f;
}

__device__ __forceinline__ void gload16(const u16* g, u16* l) {
  __builtin_amdgcn_global_load_lds(
      (const __attribute__((address_space(1))) unsigned int*)g,
      (__attribute__((address_space(3))) unsigned int*)l, 16, 0, 0);
}

#define WAITV(N) asm volatile("s_waitcnt vmcnt(" #N ")" ::: "memory")

// ---------- wave-wide sum ----------
__device__ __forceinline__ float waveSum(float v) {
  #pragma unroll
  for (int o = 32; o > 0; o >>= 1) v += __shfl_xor(v, o, 64);
  return v;
}

// ---------- block-wide sum over 256 threads ----------
__device__ __forceinline__ float blkSum256(float v, float* sb4) {
  #pragma unroll
  for (int o = 32; o > 0; o >>= 1) v += __shfl_down(v, o, 64);
  int w = threadIdx.x >> 6;
  __syncthreads();
  if ((threadIdx.x & 63) == 0) sb4[w] = v;
  __syncthreads();
  return sb4[0] + sb4[1] + sb4[2] + sb4[3];
}

// ====== MFMA 128x128 GEMM core: BK=32, 3-stage pipeline, counted vmcnt ======
template <int SAMEAB>
__device__ __forceinline__ void gemm128p(const u16* __restrict__ A,
                                         const u16* __restrict__ Bt,
                                         int lda, int k0, int k1,
                                         int row0, int col0,
                                         u16* smem, f32x4 acc[4][4]) {
  const int tid = threadIdx.x;
  const int lane = tid & 63;
  const int wv = tid >> 6;
  const int wr = (wv >> 1) << 6;
  const int wc = (wv & 1) << 6;
  const int frow = lane & 15;
  const int kg = lane >> 4;
  u16* Als = smem;                    // 3 x 4096 u16
  u16* Bls = smem + 12288;            // 3 x 4096 u16
  #pragma unroll
  for (int m = 0; m < 4; m++)
    #pragma unroll
    for (int n = 0; n < 4; n++) {
      f32x4 z = {0.f, 0.f, 0.f, 0.f};
      acc[m][n] = z;
    }
  auto stage = [&](int k, int buf) {
    #pragma unroll
    for (int i = 0; i < 2; i++) {
      int s = tid + (i << 8);
      int r = s >> 2;
      int c = (((s & 3) ^ (r & 3)) << 3);
      gload16(A + (long)(row0 + r) * lda + k + c, Als + buf * 4096 + s * 8);
    }
    if (!SAMEAB) {
      #pragma unroll
      for (int i = 0; i < 2; i++) {
        int s = tid + (i << 8);
        int r = s >> 2;
        int c = (((s & 3) ^ (r & 3)) << 3);
        gload16(Bt + (long)(col0 + r) * lda + k + c, Bls + buf * 4096 + s * 8);
      }
    }
  };
  const int nk = (k1 - k0) >> 5;
  stage(k0, 0);
  stage(k0 + 32, 1);
  for (int i = 0; i < nk; i++) {
    if (i + 2 < nk) {
      if (SAMEAB) WAITV(2); else WAITV(4);
      __builtin_amdgcn_s_barrier();
      stage(k0 + (i + 2) * 32, (i + 2) % 3);
    } else if (i + 1 < nk) {
      if (SAMEAB) WAITV(2); else WAITV(4);
      __builtin_amdgcn_s_barrier();
    } else {
      WAITV(0);
      __builtin_amdgcn_s_barrier();
    }
    const int bi = i % 3;
    const u16* Ab = Als + bi * 4096;
    const u16* Bb = SAMEAB ? Ab : (Bls + bi * 4096);
    bf16x8 af[4], bfv[4];
    #pragma unroll
    for (int m = 0; m < 4; m++) {
      int rr = wr + m * 16 + frow;
      af[m] = *(const bf16x8*)(Ab + rr * 32 + ((kg ^ (rr & 3)) << 3));
    }
    #pragma unroll
    for (int n = 0; n < 4; n++) {
      int rr = wc + n * 16 + frow;
      bfv[n] = *(const bf16x8*)(Bb + rr * 32 + ((kg ^ (rr & 3)) << 3));
    }
    __builtin_amdgcn_s_setprio(1);
    #pragma unroll
    for (int m = 0; m < 4; m++)
      #pragma unroll
      for (int n = 0; n < 4; n++)
        acc[m][n] = __builtin_amdgcn_mfma_f32_16x16x32_bf16(af[m], bfv[n], acc[m][n], 0, 0, 0);
    __builtin_amdgcn_s_setprio(0);
  }
  __syncthreads();
}

#define EPILOG_SETUP \
  const int lane = threadIdx.x & 63; \
  const int wv = threadIdx.x >> 6; \
  const int wr = (wv >> 1) << 6, wc = (wv & 1) << 6;

#define STAGE_FULL(EXPR) \
  _Pragma("unroll") \
  for (int m = 0; m < 4; m++) \
    _Pragma("unroll") \
    for (int n = 0; n < 4; n++) \
      _Pragma("unroll") \
      for (int r = 0; r < 4; r++) { \
        int lr = wr + m * 16 + ((lane >> 4) << 2) + r; \
        int lc = wc + n * 16 + (lane & 15); \
        float _a = acc[m][n][r]; \
        smem[lr * 128 + (lc ^ (((lr >> 2) & 7) << 3))] = f2b(EXPR); \
      } \
  __syncthreads();

__device__ __forceinline__ void storeC_full(const f32x4 acc[4][4], u16* smem,
                                            u16* Cb, int ldc, int row0, int col0,
                                            int wr, int wc, int lane) {
  const int tid = threadIdx.x;
  STAGE_FULL(_a)
  #pragma unroll
  for (int i = 0; i < 8; i++) {
    int idx = i * 256 + tid;
    int lr = idx >> 4, ch = idx & 15;
    uint4 v = *(const uint4*)(smem + lr * 128 + ((ch ^ ((lr >> 2) & 7)) << 3));
    *(uint4*)(Cb + (long)(row0 + lr) * ldc + col0 + ch * 8) = v;
  }
}

#define STAGE_HALF(EXPR) \
  if (wr == h * 64) { \
    _Pragma("unroll") \
    for (int m = 0; m < 4; m++) \
      _Pragma("unroll") \
      for (int n = 0; n < 4; n++) \
        _Pragma("unroll") \
        for (int r = 0; r < 4; r++) { \
          int lr = m * 16 + ((lane >> 4) << 2) + r; \
          int lc = wc + n * 16 + (lane & 15); \
          float _a = acc[m][n][r]; \
          smem[lr * 128 + (lc ^ (((lr >> 2) & 7) << 3))] = f2b(EXPR); \
        } \
  } \
  __syncthreads();

__device__ __forceinline__ void storeC_lds(const f32x4 acc[4][4], u16* smem,
                                           u16* Cb, int ldc, int row0, int col0,
                                           int wr, int wc, int lane) {
  const int tid = threadIdx.x;
  #pragma unroll
  for (int h = 0; h < 2; h++) {
    STAGE_HALF(_a)
    #pragma unroll
    for (int i = 0; i < 4; i++) {
      int idx = i * 256 + tid;
      int lr = idx >> 4, ch = idx & 15;
      uint4 v = *(const uint4*)(smem + lr * 128 + ((ch ^ ((lr >> 2) & 7)) << 3));
      *(uint4*)(Cb + (long)(row0 + h * 64 + lr) * ldc + col0 + ch * 8) = v;
    }
    __syncthreads();
  }
}

// ---------- merged preamble: cs table + all weight transposes ----------
__global__ __launch_bounds__(256)
void k_pre(const float* __restrict__ enc, const float* __restrict__ encv,
           const float* __restrict__ dec, u16* __restrict__ enct,
           u16* __restrict__ encvt, u16* __restrict__ dect,
           unsigned* __restrict__ cs) {
  __shared__ float tile[64][65];
  int id = blockIdx.x;
  int tid = threadIdx.x;
  if (id < 4096) {
    int idx = id * 256 + tid;
    int t = idx >> 11;
    int k = idx & 2047;
    float freq = exp2f(-(float)k * (1.0f / 128.0f));
    float ph = (float)t * freq;
    cs[idx] = (unsigned)f2b(cosf(ph)) | ((unsigned)f2b(sinf(ph)) << 16);
    return;
  }
  const float* src; u16* dst; long zoff; int r0, c0, Rd, Cd;
  if (id < 6144) {
    int q = id - 4096;
    int x = q & 63, y = (q >> 6) & 3, z = q >> 8;
    src = (z < 4) ? enc : encv;
    dst = (z < 4) ? enct : encvt;
    zoff = (long)(z & 3) * D_ * NI_;
    r0 = y * 64; c0 = x * 64; Rd = D_; Cd = NI_;
  } else {
    int q = id - 6144;
    int x = q & 3, y = q >> 2;
    src = dec; dst = dect; zoff = 0;
    r0 = y * 64; c0 = x * 64; Rd = NH_ * NI_; Cd = D_;
  }
  int tr = tid >> 4, tc4 = (tid & 15) * 4;
  #pragma unroll
  for (int i = 0; i < 4; i++) {
    int r = tr + i * 16;
    f32x4 v = *(const f32x4*)(src + zoff + (long)(r0 + r) * Cd + c0 + tc4);
    tile[r][tc4 + 0] = v.x; tile[r][tc4 + 1] = v.y;
    tile[r][tc4 + 2] = v.z; tile[r][tc4 + 3] = v.w;
  }
  __syncthreads();
  #pragma unroll
  for (int i = 0; i < 4; i++) {
    int c = tr + i * 16;
    ushort4 o;
    o.x = f2b(tile[tc4 + 0][c]); o.y = f2b(tile[tc4 + 1][c]);
    o.z = f2b(tile[tc4 + 2][c]); o.w = f2b(tile[tc4 + 3][c]);
    *(ushort4*)(dst + zoff + (long)(c0 + c) * Rd + r0 + tc4) = o;
  }
}

// ---------- input proj + LN: 2 rows/block, K split across 4 waves ----------
__global__ __launch_bounds__(256)
void k_input(const float* __restrict__ x, const float* __restrict__ W,
             const float* __restrict__ b, float* __restrict__ hf,
             u16* __restrict__ hbf, u16* __restrict__ hT) {
  __shared__ float xr[2][IN_DIM_];
  __shared__ float part[4][2][D_];
  __shared__ float sb[4];
  __shared__ u16 tb2[2][D_];
  int bt0 = blockIdx.x * 2;
  int tid = threadIdx.x;
  int wv = tid >> 6, l = tid & 63;
  for (int i = tid; i < 2 * IN_DIM_; i += 256)
    xr[i / IN_DIM_][i % IN_DIM_] = x[(long)bt0 * IN_DIM_ + i];
  __syncthreads();
  float a00 = 0, a01 = 0, a02 = 0, a03 = 0;
  float a10 = 0, a11 = 0, a12 = 0, a13 = 0;
  int kbeg = wv * 93, kend = kbeg + 93;
  for (int k = kbeg; k < kend; k++) {
    const float* Wr = W + (long)k * D_ + l;
    float w0 = Wr[0], w1 = Wr[64], w2 = Wr[128], w3 = Wr[192];
    float x0 = xr[0][k], x1 = xr[1][k];
    a00 += x0 * w0; a01 += x0 * w1; a02 += x0 * w2; a03 += x0 * w3;
    a10 += x1 * w0; a11 += x1 * w1; a12 += x1 * w2; a13 += x1 * w3;
  }
  part[wv][0][l] = a00; part[wv][0][l + 64] = a01;
  part[wv][0][l + 128] = a02; part[wv][0][l + 192] = a03;
  part[wv][1][l] = a10; part[wv][1][l + 64] = a11;
  part[wv][1][l + 128] = a12; part[wv][1][l + 192] = a13;
  __syncthreads();
  int d = tid;
  #pragma unroll
  for (int r = 0; r < 2; r++) {
    float s = part[0][r][d] + part[1][r][d] + part[2][r][d] + part[3][r][d] + b[d];
    float mean = blkSum256(s, sb) * (1.0f / D_);
    float c = s - mean;
    float var = blkSum256(c * c, sb) * (1.0f / D_);
    float out = c * rsqrtf(var + EPS_);
    int bt = bt0 + r;
    hf[(long)bt * D_ + d] = out;
    hbf[(long)bt * D_ + d] = f2b(out);
    tb2[r][d] = f2b(out);
  }
  __syncthreads();
  // coalesced transposed write: 2 consecutive t per d -> one u32 store
  unsigned tw = (unsigned)tb2[0][d] | ((unsigned)tb2[1][d] << 16);
  *(unsigned*)(hT + ((long)(bt0 >> 9) * D_ + d) * T_ + (bt0 & 511)) = tw;
}

// ---------- qr = rope(relu(h@enc)) ----------
// grid (32, 8, 4); LDS 48KB caps 3 blocks/CU -> bound VGPR for 3
__global__ __launch_bounds__(256, 3)
void g_enc(const u16* __restrict__ hbf, const u16* __restrict__ enct,
           const unsigned* __restrict__ cs, u16* __restrict__ qr) {
  __shared__ u16 smem[24576];
  int head = blockIdx.z;
  int row0 = blockIdx.y * 128, col0 = blockIdx.x * 128;
  f32x4 acc[4][4];
  gemm128p<0>(hbf, enct + (long)head * NI_ * D_, D_, 0, D_, row0, col0, smem, acc);
  EPILOG_SETUP
  const int tid = threadIdx.x;
  STAGE_FULL(fmaxf(_a, 0.f))
  #pragma unroll
  for (int i = 0; i < 8; i++) {
    int idx = i * 256 + tid;
    int lr = idx >> 4, ch = idx & 15;
    uint4 v = *(const uint4*)(smem + lr * 128 + ((ch ^ ((lr >> 2) & 7)) << 3));
    int gr = row0 + lr;
    int b = gr >> 9, t = gr & 511;
    int gcol = col0 + ch * 8;
    uint4 csv = *(const uint4*)(cs + (long)t * (NI_ / 2) + (gcol >> 1));
    const unsigned* pv = &v.x; const unsigned* pc = &csv.x;
    unsigned o[4];
    #pragma unroll
    for (int j = 0; j < 4; j++) {
      float v0 = b2f((u16)pv[j]), v1 = b2f((u16)(pv[j] >> 16));
      float cc = b2f((u16)pc[j]), ss = b2f((u16)(pc[j] >> 16));
      o[j] = (unsigned)f2b(v0 * cc - v1 * ss) | ((unsigned)f2b(v0 * ss + v1 * cc) << 16);
    }
    long qri = (((long)(b * NH_ + head)) * T_ + t) * NI_ + gcol;
    *(uint4*)(qr + qri) = make_uint4(o[0], o[1], o[2], o[3]);
  }
}

// ---------- scores partials (bf16, SYMMETRIC, split-K 4): upper-tri + mirror ----------
// grid (10, 1, 32)
__global__ __launch_bounds__(256, 3)
void g_scores(const u16* __restrict__ qr, u16* __restrict__ scpb) {
  __shared__ u16 smem[24576];
  int tix = blockIdx.x;
  int by = (tix < 4) ? 0 : (tix < 7) ? 1 : (tix < 9) ? 2 : 3;
  int sub = (by == 0) ? 0 : (by == 1) ? 3 : (by == 2) ? 5 : 6;
  int bx = tix - sub;
  int z2 = blockIdx.z;
  int z = z2 >> 2, ks = z2 & 3;
  const u16* A = qr + (long)z * T_ * NI_;
  int row0 = by * 128, col0 = bx * 128;
  f32x4 acc[4][4];
  if (by == bx)
    gemm128p<1>(A, A, NI_, ks * 1024, ks * 1024 + 1024, row0, col0, smem, acc);
  else
    gemm128p<0>(A, A, NI_, ks * 1024, ks * 1024 + 1024, row0, col0, smem, acc);
  EPILOG_SETUP
  u16* Cb = scpb + (long)(ks * 8 + z) * T_ * T_;
  storeC_full(acc, smem, Cb, T_, row0, col0, wr, wc, lane);
  if (by != bx) {
    // mirrored tile C[s][t] = C[t][s]: stage C^T in LDS, store coalesced rows
    __syncthreads();
    #pragma unroll
    for (int m = 0; m < 4; m++)
      #pragma unroll
      for (int n = 0; n < 4; n++) {
        int lcC = wc + n * 16 + (lane & 15);          // C col -> C^T row
        int lr0 = wr + m * 16 + ((lane >> 4) << 2);   // C row base (aligned 4)
        u16* dstp = smem + lcC * 128 + (lr0 ^ ((lcC & 7) << 3));
        dstp[0] = f2b(acc[m][n][0]);
        dstp[1] = f2b(acc[m][n][1]);
        dstp[2] = f2b(acc[m][n][2]);
        dstp[3] = f2b(acc[m][n][3]);
      }
    __syncthreads();
    const int tid2 = threadIdx.x;
    #pragma unroll
    for (int i = 0; i < 8; i++) {
      int idx = i * 256 + tid2;
      int lrr = idx >> 4, ch = idx & 15;
      uint4 v = *(const uint4*)(smem + lrr * 128 + ((ch ^ (lrr & 7)) << 3));
      *(uint4*)(Cb + (long)(col0 + lrr) * T_ + row0 + ch * 8) = v;
    }
  }
}

// ---------- yKV partials, fused 4-partial score sum in A-staging ----------
// grid (2, 4, 32)
__global__ __launch_bounds__(256, 3)
void g_ykv(const u16* __restrict__ scpb, const u16* __restrict__ hT,
           u16* __restrict__ ykvpb) {
  __shared__ u16 smem[16384];
  u16* Als = smem;
  u16* Bls = smem + 8192;
  int z2 = blockIdx.z;
  int z = z2 >> 2, ks = z2 & 3;
  int b = z >> 2;
  int row0 = blockIdx.y * 128, col0 = blockIdx.x * 128;
  const long SL = (long)8 * T_ * T_;
  const u16* Ab = scpb + (long)z * T_ * T_;
  const u16* Bt = hT + (long)b * D_ * T_;
  const int tid = threadIdx.x;
  const int lane = tid & 63;
  const int wv = tid >> 6;
  const int wr = (wv >> 1) << 6, wc = (wv & 1) << 6;
  const int frow = lane & 15;
  const int kg = lane >> 4;
  const int sw = frow & 7;
  f32x4 acc[4][4];
  #pragma unroll
  for (int m = 0; m < 4; m++)
    #pragma unroll
    for (int n = 0; n < 4; n++) {
      f32x4 zz = {0.f, 0.f, 0.f, 0.f};
      acc[m][n] = zz;
    }
  const int ar = tid >> 1;
  const int ac0 = (tid & 1) << 2;
  for (int k = ks * 128; k < ks * 128 + 128; k += 64) {
    long gb = (long)(row0 + ar) * T_ + k;
    #pragma unroll
    for (int j = 0; j < 4; j++) {
      int jj = ac0 + j;
      long ga = gb + (jj << 3);
      uint4 p0 = *(const uint4*)(Ab + ga);
      uint4 p1 = *(const uint4*)(Ab + SL + ga);
      uint4 p2 = *(const uint4*)(Ab + 2 * SL + ga);
      uint4 p3 = *(const uint4*)(Ab + 3 * SL + ga);
      const unsigned* q0 = &p0.x; const unsigned* q1 = &p1.x;
      const unsigned* q2 = &p2.x; const unsigned* q3 = &p3.x;
      unsigned o[4];
      #pragma unroll
      for (int w = 0; w < 4; w++) {
        float lo = b2f((u16)q0[w]) + b2f((u16)q1[w]) + b2f((u16)q2[w]) + b2f((u16)q3[w]);
        float hi = b2f((u16)(q0[w] >> 16)) + b2f((u16)(q1[w] >> 16)) +
                   b2f((u16)(q2[w] >> 16)) + b2f((u16)(q3[w] >> 16));
        o[w] = (unsigned)f2b(lo) | ((unsigned)f2b(hi) << 16);
      }
      *(uint4*)(Als + ar * 64 + ((jj ^ (ar & 7)) << 3)) = make_uint4(o[0], o[1], o[2], o[3]);
    }
    #pragma unroll
    for (int i = 0; i < 4; i++) {
      int s = tid + (i << 8);
      int r = s >> 3;
      int c = (((s & 7) ^ (r & 7)) << 3);
      gload16(Bt + (long)(col0 + r) * T_ + k + c, Bls + s * 8);
    }
    __syncthreads();
    #pragma unroll
    for (int kk = 0; kk < 2; kk++) {
      const int slot = ((((kk << 2) + kg) ^ sw) << 3);
      bf16x8 af[4], bfv[4];
      #pragma unroll
      for (int m = 0; m < 4; m++)
        af[m] = *(const bf16x8*)(Als + (wr + m * 16 + frow) * 64 + slot);
      #pragma unroll
      for (int n = 0; n < 4; n++)
        bfv[n] = *(const bf16x8*)(Bls + (wc + n * 16 + frow) * 64 + slot);
      __builtin_amdgcn_s_setprio(1);
      #pragma unroll
      for (int m = 0; m < 4; m++)
        #pragma unroll
        for (int n = 0; n < 4; n++)
          acc[m][n] = __builtin_amdgcn_mfma_f32_16x16x32_bf16(af[m], bfv[n], acc[m][n], 0, 0, 0);
      __builtin_amdgcn_s_setprio(0);
    }
    __syncthreads();
  }
  storeC_lds(acc, smem, ykvpb + (long)(ks * 8 + z) * T_ * D_, D_, row0, col0, wr, wc, lane);
}

// ---------- sum 4 yKV partials + LN -> bf16 (wave per row) ----------
__global__ __launch_bounds__(256)
void k_lnykv(const u16* __restrict__ ykvpb, u16* __restrict__ ykvb) {
  int row = blockIdx.x * 4 + (threadIdx.x >> 6);
  int lane = threadIdx.x & 63;
  const long SL = (long)8 * T_ * D_;
  long base = (long)row * D_ + lane * 4;
  float v0 = 0.f, v1 = 0.f, v2 = 0.f, v3 = 0.f;
  #pragma unroll
  for (int p = 0; p < 4; p++) {
    uint2 w = *(const uint2*)(ykvpb + p * SL + base);
    v0 += b2f((u16)w.x); v1 += b2f((u16)(w.x >> 16));
    v2 += b2f((u16)w.y); v3 += b2f((u16)(w.y >> 16));
  }
  float mean = waveSum(v0 + v1 + v2 + v3) * (1.0f / D_);
  float c0 = v0 - mean, c1 = v1 - mean, c2 = v2 - mean, c3 = v3 - mean;
  float var = waveSum(c0 * c0 + c1 * c1 + c2 * c2 + c3 * c3) * (1.0f / D_);
  float rs = rsqrtf(var + EPS_);
  uint2 o;
  o.x = (unsigned)f2b(c0 * rs) | ((unsigned)f2b(c1 * rs) << 16);
  o.y = (unsigned)f2b(c2 * rs) | ((unsigned)f2b(c3 * rs) << 16);
  *(uint2*)(ykvb + base) = o;
}

// ---------- xy = relu(yKV@encv) * relu(inv_rope(qr)) ----------
// grid (32, 4, 8)
__global__ __launch_bounds__(256, 3)
void g_ysp(const u16* __restrict__ ykvb, const u16* __restrict__ encvt,
           const u16* __restrict__ qr, const unsigned* __restrict__ cs,
           u16* __restrict__ xy) {
  __shared__ u16 smem[24576];
  int z = blockIdx.z;
  int b = z >> 2, head = z & 3;
  int row0 = blockIdx.y * 128, col0 = blockIdx.x * 128;
  f32x4 acc[4][4];
  gemm128p<0>(ykvb + (long)z * T_ * D_, encvt + (long)head * NI_ * D_, D_,
              0, D_, row0, col0, smem, acc);
  EPILOG_SETUP
  const int tid = threadIdx.x;
  STAGE_FULL(fmaxf(_a, 0.f))
  #pragma unroll
  for (int i = 0; i < 8; i++) {
    int idx = i * 256 + tid;
    int lr = idx >> 4, ch = idx & 15;
    uint4 v = *(const uint4*)(smem + lr * 128 + ((ch ^ ((lr >> 2) & 7)) << 3));
    int t = row0 + lr;
    int gcol = col0 + ch * 8;
    uint4 qv = *(const uint4*)(qr + ((long)z * T_ + t) * NI_ + gcol);
    uint4 csv = *(const uint4*)(cs + (long)t * (NI_ / 2) + (gcol >> 1));
    const unsigned* pv = &v.x; const unsigned* pq = &qv.x; const unsigned* pc = &csv.x;
    unsigned o[4];
    #pragma unroll
    for (int j = 0; j < 4; j++) {
      float v0 = b2f((u16)pv[j]), v1 = b2f((u16)(pv[j] >> 16));
      float q0 = b2f((u16)pq[j]), q1 = b2f((u16)(pq[j] >> 16));
      float cc = b2f((u16)pc[j]), ss = b2f((u16)(pc[j] >> 16));
      float hs0 = fmaxf(cc * q0 + ss * q1, 0.f);
      float hs1 = fmaxf(cc * q1 - ss * q0, 0.f);
      o[j] = (unsigned)f2b(hs0 * v0) | ((unsigned)f2b(hs1 * v1) << 16);
    }
    long xyi = ((long)b * T_ + t) * (NH_ * NI_) + head * NI_ + gcol;
    *(uint4*)(xy + xyi) = make_uint4(o[0], o[1], o[2], o[3]);
  }
}

// ---------- yMLP partials (bf16): split-K 16 ----------
// grid (2, 8, 16)
__global__ __launch_bounds__(256, 3)
void g_ymlp(const u16* __restrict__ xy, const u16* __restrict__ dect,
            u16* __restrict__ ymlppb) {
  __shared__ u16 smem[24576];
  int ks = blockIdx.z;
  int row0 = blockIdx.y * 128, col0 = blockIdx.x * 128;
  f32x4 acc[4][4];
  gemm128p<0>(xy, dect, NH_ * NI_, ks * 1024, ks * 1024 + 1024, row0, col0, smem, acc);
  EPILOG_SETUP
  storeC_full(acc, smem, ymlppb + (long)ks * (B_ * T_) * D_, D_, row0, col0, wr, wc, lane);
}

// ---------- h = LN(h + LN(sum of 16 partials)) (wave per row) ----------
__global__ __launch_bounds__(256)
void k_dln(const u16* __restrict__ ymlppb, float* __restrict__ hf,
           u16* __restrict__ hbf, u16* __restrict__ hT) {
  __shared__ u16 tb[4][D_];
  int wv = threadIdx.x >> 6;
  int bt = blockIdx.x * 4 + wv;
  int lane = threadIdx.x & 63;
  const long SL = (long)(B_ * T_) * D_;
  long base = (long)bt * D_ + lane * 4;
  float v0 = 0.f, v1 = 0.f, v2 = 0.f, v3 = 0.f;
  #pragma unroll
  for (int p = 0; p < 16; p++) {
    uint2 w = *(const uint2*)(ymlppb + p * SL + base);
    v0 += b2f((u16)w.x); v1 += b2f((u16)(w.x >> 16));
    v2 += b2f((u16)w.y); v3 += b2f((u16)(w.y >> 16));
  }
  float mean = waveSum(v0 + v1 + v2 + v3) * (1.0f / D_);
  float c0 = v0 - mean, c1 = v1 - mean, c2 = v2 - mean, c3 = v3 - mean;
  float var = waveSum(c0 * c0 + c1 * c1 + c2 * c2 + c3 * c3) * (1.0f / D_);
  float rs = rsqrtf(var + EPS_);
  f32x4 hv = *(const f32x4*)(hf + base);
  float w0 = hv.x + c0 * rs, w1 = hv.y + c1 * rs;
  float w2 = hv.z + c2 * rs, w3 = hv.w + c3 * rs;
  float m2 = waveSum(w0 + w1 + w2 + w3) * (1.0f / D_);
  float e0 = w0 - m2, e1 = w1 - m2, e2 = w2 - m2, e3 = w3 - m2;
  float va2 = waveSum(e0 * e0 + e1 * e1 + e2 * e2 + e3 * e3) * (1.0f / D_);
  float rs2 = rsqrtf(va2 + EPS_);
  float o0 = e0 * rs2, o1 = e1 * rs2, o2 = e2 * rs2, o3 = e3 * rs2;
  f32x4 of = {o0, o1, o2, o3};
  *(f32x4*)(hf + base) = of;
  uint2 ob;
  ob.x = (unsigned)f2b(o0) | ((unsigned)f2b(o1) << 16);
  ob.y = (unsigned)f2b(o2) | ((unsigned)f2b(o3) << 16);
  *(uint2*)(hbf + base) = ob;
  int d0 = lane * 4;
  tb[wv][d0 + 0] = f2b(o0);
  tb[wv][d0 + 1] = f2b(o1);
  tb[wv][d0 + 2] = f2b(o2);
  tb[wv][d0 + 3] = f2b(o3);
  __syncthreads();
  // coalesced transposed write: 4 consecutive t per d -> one 8B store
  int d = threadIdx.x;
  int bt0 = blockIdx.x * 4;
  uint2 tw;
  tw.x = (unsigned)tb[0][d] | ((unsigned)tb[1][d] << 16);
  tw.y = (unsigned)tb[2][d] | ((unsigned)tb[3][d] << 16);
  *(uint2*)(hT + ((long)(bt0 >> 9) * D_ + d) * T_ + (bt0 & 511)) = tw;
}

// ---------- head: 2 rows/block, K split across 4 waves ----------
__global__ __launch_bounds__(256)
void k_head(const float* __restrict__ h, const float* __restrict__ W,
            const float* __restrict__ bb, float* __restrict__ out) {
  __shared__ float hr[2][D_];
  __shared__ float part[4][2][384];
  int bt0 = blockIdx.x * 2;
  int tid = threadIdx.x;
  int wv = tid >> 6, l = tid & 63;
  for (int i = tid; i < 2 * D_; i += 256)
    hr[i >> 8][i & 255] = h[(long)bt0 * D_ + i];
  __syncthreads();
  float a0[6] = {0.f, 0.f, 0.f, 0.f, 0.f, 0.f};
  float a1[6] = {0.f, 0.f, 0.f, 0.f, 0.f, 0.f};
  int kbeg = wv * 64, kend = kbeg + 64;
  for (int k = kbeg; k < kend; k++) {
    float x0 = hr[0][k], x1 = hr[1][k];
    const float* Wr = W + (long)k * IN_DIM_;
    #pragma unroll
    for (int jj = 0; jj < 6; jj++) {
      int j = l + jj * 64;
      float w = (j < IN_DIM_) ? Wr[j] : 0.f;
      a0[jj] += x0 * w;
      a1[jj] += x1 * w;
    }
  }
  #pragma unroll
  for (int jj = 0; jj < 6; jj++) {
    int j = l + jj * 64;
    part[wv][0][j] = a0[jj];
    part[wv][1][j] = a1[jj];
  }
  __syncthreads();
  #pragma unroll
  for (int pass = 0; pass < 2; pass++) {
    int j = tid + pass * 256;
    if (j < IN_DIM_) {
      float s0 = part[0][0][j] + part[1][0][j] + part[2][0][j] + part[3][0][j] + bb[j];
      float s1 = part[0][1][j] + part[1][1][j] + part[2][1][j] + part[3][1][j] + bb[j];
      out[(long)bt0 * IN_DIM_ + j] = s0;
      out[(long)(bt0 + 1) * IN_DIM_ + j] = s1;
    }
  }
}

extern "C" void kernel_launch(void* const* d_in, const int* in_sizes, int n_in,
                              void* d_out, int out_size, void* d_ws, size_t ws_size,
                              hipStream_t stream) {
  const float* x    = (const float*)d_in[0];
  const float* in_W = (const float*)d_in[1];
  const float* in_b = (const float*)d_in[2];
  const float* enc  = (const float*)d_in[3];
  const float* encv = (const float*)d_in[4];
  const float* dec  = (const float*)d_in[5];
  const float* hW   = (const float*)d_in[6];
  const float* hb   = (const float*)d_in[7];
  float* out = (float*)d_out;

  char* p = (char*)d_ws;
  auto alloc = [&](size_t bytes) { char* r = p; p += (bytes + 255) & ~(size_t)255; return r; };
  unsigned* cs   = (unsigned*)alloc((size_t)T_ * (NI_ / 2) * 4);     // 4 MB
  float* hf      = (float*)alloc((size_t)B_ * T_ * D_ * 4);          // 1 MB
  u16*   hbf     = (u16*)  alloc((size_t)B_ * T_ * D_ * 2);
  u16*   hT      = (u16*)  alloc((size_t)B_ * D_ * T_ * 2);
  u16*   enct    = (u16*)  alloc((size_t)NH_ * D_ * NI_ * 2);        // 8 MB
  u16*   encvt   = (u16*)  alloc((size_t)NH_ * D_ * NI_ * 2);        // 8 MB
  u16*   dect    = (u16*)  alloc((size_t)NH_ * NI_ * D_ * 2);        // 8 MB
  u16*   qr      = (u16*)  alloc((size_t)B_ * NH_ * T_ * NI_ * 2);   // 32 MB
  u16*   xy      = (u16*)  alloc((size_t)B_ * T_ * NH_ * NI_ * 2);   // 32 MB
  u16*   scpb    = (u16*)  alloc((size_t)4 * 8 * T_ * T_ * 2);       // 16 MB
  u16*   ykvpb   = (u16*)  alloc((size_t)4 * 8 * T_ * D_ * 2);       // 8 MB
  u16*   ykvb    = (u16*)  alloc((size_t)8 * T_ * D_ * 2);           // 2 MB
  u16*   ymlppb  = (u16*)  alloc((size_t)16 * B_ * T_ * D_ * 2);     // 8 MB

  k_pre<<<dim3(7168), dim3(256), 0, stream>>>(enc, encv, dec, enct, encvt, dect, cs);
  k_input<<<dim3(B_ * T_ / 2), dim3(256), 0, stream>>>(x, in_W, in_b, hf, hbf, hT);

  for (int l = 0; l < NL_; l++) {
    g_enc<<<dim3(32, 8, 4), dim3(256), 0, stream>>>(hbf, enct, cs, qr);
    g_scores<<<dim3(10, 1, 32), dim3(256), 0, stream>>>(qr, scpb);
    g_ykv<<<dim3(2, 4, 32), dim3(256), 0, stream>>>(scpb, hT, ykvpb);
    k_lnykv<<<dim3(1024), dim3(256), 0, stream>>>(ykvpb, ykvb);
    g_ysp<<<dim3(32, 4, 8), dim3(256), 0, stream>>>(ykvb, encvt, qr, cs, xy);
    g_ymlp<<<dim3(2, 8, 16), dim3(256), 0, stream>>>(xy, dect, ymlppb);
    k_dln<<<dim3(256), dim3(256), 0, stream>>>(ymlppb, hf, hbf, hT);
  }

  k_head<<<dim3(B_ * T_ / 2), dim3(256), 0, stream>>>(hf, hW, hb, out);
}

// Round 14
// 715.045 us; speedup vs baseline: 1.0077x; 1.0077x over previous
//
#include <hip/hip_runtime.h>
#include <math.h>

#define B_ 2
#define T_ 512
#define D_ 256
#define NH_ 4
#define NI_ 4096
#define IN_DIM_ 372
#define NL_ 6
#define EPS_ 1e-5f

typedef unsigned short u16;
typedef __attribute__((ext_vector_type(4))) float f32x4;
typedef __attribute__((ext_vector_type(8))) short bf16x8;

__device__ __forceinline__ u16 f2b(float f) {
  union { float f; unsigned u; } v; v.f = f;
  unsigned r = v.u + 0x7fffu + ((v.u >> 16) & 1u);
  return (u16)(r >> 16);
}
__device__ __forceinline__ float b2f(u16 s) {
  union { unsigned u; float f; } v; v.u = ((unsigned)s) << 16;
  return v.f;
}

__device__ __forceinline__ void gload16(const u16* g, u16* l) {
  __builtin_amdgcn_global_load_lds(
      (const __attribute__((address_space(1))) unsigned int*)g,
      (__attribute__((address_space(3))) unsigned int*)l, 16, 0, 0);
}

#define WAITV(N) asm volatile("s_waitcnt vmcnt(" #N ")" ::: "memory")

// ---------- wave-wide sum ----------
__device__ __forceinline__ float waveSum(float v) {
  #pragma unroll
  for (int o = 32; o > 0; o >>= 1) v += __shfl_xor(v, o, 64);
  return v;
}

// ---------- block-wide sum over 256 threads ----------
__device__ __forceinline__ float blkSum256(float v, float* sb4) {
  #pragma unroll
  for (int o = 32; o > 0; o >>= 1) v += __shfl_down(v, o, 64);
  int w = threadIdx.x >> 6;
  __syncthreads();
  if ((threadIdx.x & 63) == 0) sb4[w] = v;
  __syncthreads();
  return sb4[0] + sb4[1] + sb4[2] + sb4[3];
}

// ====== MFMA 128x128 GEMM core: BK=32, 3-stage pipeline, counted vmcnt ======
template <int SAMEAB>
__device__ __forceinline__ void gemm128p(const u16* __restrict__ A,
                                         const u16* __restrict__ Bt,
                                         int lda, int k0, int k1,
                                         int row0, int col0,
                                         u16* smem, f32x4 acc[4][4]) {
  const int tid = threadIdx.x;
  const int lane = tid & 63;
  const int wv = tid >> 6;
  const int wr = (wv >> 1) << 6;
  const int wc = (wv & 1) << 6;
  const int frow = lane & 15;
  const int kg = lane >> 4;
  u16* Als = smem;                    // 3 x 4096 u16
  u16* Bls = smem + 12288;            // 3 x 4096 u16
  #pragma unroll
  for (int m = 0; m < 4; m++)
    #pragma unroll
    for (int n = 0; n < 4; n++) {
      f32x4 z = {0.f, 0.f, 0.f, 0.f};
      acc[m][n] = z;
    }
  auto stage = [&](int k, int buf) {
    #pragma unroll
    for (int i = 0; i < 2; i++) {
      int s = tid + (i << 8);
      int r = s >> 2;
      int c = (((s & 3) ^ (r & 3)) << 3);
      gload16(A + (long)(row0 + r) * lda + k + c, Als + buf * 4096 + s * 8);
    }
    if (!SAMEAB) {
      #pragma unroll
      for (int i = 0; i < 2; i++) {
        int s = tid + (i << 8);
        int r = s >> 2;
        int c = (((s & 3) ^ (r & 3)) << 3);
        gload16(Bt + (long)(col0 + r) * lda + k + c, Bls + buf * 4096 + s * 8);
      }
    }
  };
  const int nk = (k1 - k0) >> 5;
  stage(k0, 0);
  stage(k0 + 32, 1);
  for (int i = 0; i < nk; i++) {
    if (i + 2 < nk) {
      if (SAMEAB) WAITV(2); else WAITV(4);
      __builtin_amdgcn_s_barrier();
      stage(k0 + (i + 2) * 32, (i + 2) % 3);
    } else if (i + 1 < nk) {
      if (SAMEAB) WAITV(2); else WAITV(4);
      __builtin_amdgcn_s_barrier();
    } else {
      WAITV(0);
      __builtin_amdgcn_s_barrier();
    }
    const int bi = i % 3;
    const u16* Ab = Als + bi * 4096;
    const u16* Bb = SAMEAB ? Ab : (Bls + bi * 4096);
    bf16x8 af[4], bfv[4];
    #pragma unroll
    for (int m = 0; m < 4; m++) {
      int rr = wr + m * 16 + frow;
      af[m] = *(const bf16x8*)(Ab + rr * 32 + ((kg ^ (rr & 3)) << 3));
    }
    #pragma unroll
    for (int n = 0; n < 4; n++) {
      int rr = wc + n * 16 + frow;
      bfv[n] = *(const bf16x8*)(Bb + rr * 32 + ((kg ^ (rr & 3)) << 3));
    }
    __builtin_amdgcn_s_setprio(1);
    #pragma unroll
    for (int m = 0; m < 4; m++)
      #pragma unroll
      for (int n = 0; n < 4; n++)
        acc[m][n] = __builtin_amdgcn_mfma_f32_16x16x32_bf16(af[m], bfv[n], acc[m][n], 0, 0, 0);
    __builtin_amdgcn_s_setprio(0);
  }
  __syncthreads();
}

#define EPILOG_SETUP \
  const int lane = threadIdx.x & 63; \
  const int wv = threadIdx.x >> 6; \
  const int wr = (wv >> 1) << 6, wc = (wv & 1) << 6;

#define STAGE_FULL(EXPR) \
  _Pragma("unroll") \
  for (int m = 0; m < 4; m++) \
    _Pragma("unroll") \
    for (int n = 0; n < 4; n++) \
      _Pragma("unroll") \
      for (int r = 0; r < 4; r++) { \
        int lr = wr + m * 16 + ((lane >> 4) << 2) + r; \
        int lc = wc + n * 16 + (lane & 15); \
        float _a = acc[m][n][r]; \
        smem[lr * 128 + (lc ^ (((lr >> 2) & 7) << 3))] = f2b(EXPR); \
      } \
  __syncthreads();

__device__ __forceinline__ void storeC_full(const f32x4 acc[4][4], u16* smem,
                                            u16* Cb, int ldc, int row0, int col0,
                                            int wr, int wc, int lane) {
  const int tid = threadIdx.x;
  STAGE_FULL(_a)
  #pragma unroll
  for (int i = 0; i < 8; i++) {
    int idx = i * 256 + tid;
    int lr = idx >> 4, ch = idx & 15;
    uint4 v = *(const uint4*)(smem + lr * 128 + ((ch ^ ((lr >> 2) & 7)) << 3));
    *(uint4*)(Cb + (long)(row0 + lr) * ldc + col0 + ch * 8) = v;
  }
}

#define STAGE_HALF(EXPR) \
  if (wr == h * 64) { \
    _Pragma("unroll") \
    for (int m = 0; m < 4; m++) \
      _Pragma("unroll") \
      for (int n = 0; n < 4; n++) \
        _Pragma("unroll") \
        for (int r = 0; r < 4; r++) { \
          int lr = m * 16 + ((lane >> 4) << 2) + r; \
          int lc = wc + n * 16 + (lane & 15); \
          float _a = acc[m][n][r]; \
          smem[lr * 128 + (lc ^ (((lr >> 2) & 7) << 3))] = f2b(EXPR); \
        } \
  } \
  __syncthreads();

__device__ __forceinline__ void storeC_lds(const f32x4 acc[4][4], u16* smem,
                                           u16* Cb, int ldc, int row0, int col0,
                                           int wr, int wc, int lane) {
  const int tid = threadIdx.x;
  #pragma unroll
  for (int h = 0; h < 2; h++) {
    STAGE_HALF(_a)
    #pragma unroll
    for (int i = 0; i < 4; i++) {
      int idx = i * 256 + tid;
      int lr = idx >> 4, ch = idx & 15;
      uint4 v = *(const uint4*)(smem + lr * 128 + ((ch ^ ((lr >> 2) & 7)) << 3));
      *(uint4*)(Cb + (long)(row0 + h * 64 + lr) * ldc + col0 + ch * 8) = v;
    }
    __syncthreads();
  }
}

// ---------- merged preamble: cs table + all weight transposes ----------
__global__ __launch_bounds__(256)
void k_pre(const float* __restrict__ enc, const float* __restrict__ encv,
           const float* __restrict__ dec, u16* __restrict__ enct,
           u16* __restrict__ encvt, u16* __restrict__ dect,
           unsigned* __restrict__ cs) {
  __shared__ float tile[64][65];
  int id = blockIdx.x;
  int tid = threadIdx.x;
  if (id < 4096) {
    int idx = id * 256 + tid;
    int t = idx >> 11;
    int k = idx & 2047;
    float freq = exp2f(-(float)k * (1.0f / 128.0f));
    float ph = (float)t * freq;
    cs[idx] = (unsigned)f2b(cosf(ph)) | ((unsigned)f2b(sinf(ph)) << 16);
    return;
  }
  const float* src; u16* dst; long zoff; int r0, c0, Rd, Cd;
  if (id < 6144) {
    int q = id - 4096;
    int x = q & 63, y = (q >> 6) & 3, z = q >> 8;
    src = (z < 4) ? enc : encv;
    dst = (z < 4) ? enct : encvt;
    zoff = (long)(z & 3) * D_ * NI_;
    r0 = y * 64; c0 = x * 64; Rd = D_; Cd = NI_;
  } else {
    int q = id - 6144;
    int x = q & 3, y = q >> 2;
    src = dec; dst = dect; zoff = 0;
    r0 = y * 64; c0 = x * 64; Rd = NH_ * NI_; Cd = D_;
  }
  int tr = tid >> 4, tc4 = (tid & 15) * 4;
  #pragma unroll
  for (int i = 0; i < 4; i++) {
    int r = tr + i * 16;
    f32x4 v = *(const f32x4*)(src + zoff + (long)(r0 + r) * Cd + c0 + tc4);
    tile[r][tc4 + 0] = v.x; tile[r][tc4 + 1] = v.y;
    tile[r][tc4 + 2] = v.z; tile[r][tc4 + 3] = v.w;
  }
  __syncthreads();
  #pragma unroll
  for (int i = 0; i < 4; i++) {
    int c = tr + i * 16;
    ushort4 o;
    o.x = f2b(tile[tc4 + 0][c]); o.y = f2b(tile[tc4 + 1][c]);
    o.z = f2b(tile[tc4 + 2][c]); o.w = f2b(tile[tc4 + 3][c]);
    *(ushort4*)(dst + zoff + (long)(c0 + c) * Rd + r0 + tc4) = o;
  }
}

// ---------- input proj + LN: 2 rows/block, K split across 4 waves ----------
__global__ __launch_bounds__(256)
void k_input(const float* __restrict__ x, const float* __restrict__ W,
             const float* __restrict__ b, float* __restrict__ hf,
             u16* __restrict__ hbf, u16* __restrict__ hT) {
  __shared__ float xr[2][IN_DIM_];
  __shared__ float part[4][2][D_];
  __shared__ float sb[4];
  __shared__ u16 tb2[2][D_];
  int bt0 = blockIdx.x * 2;
  int tid = threadIdx.x;
  int wv = tid >> 6, l = tid & 63;
  for (int i = tid; i < 2 * IN_DIM_; i += 256)
    xr[i / IN_DIM_][i % IN_DIM_] = x[(long)bt0 * IN_DIM_ + i];
  __syncthreads();
  float a00 = 0, a01 = 0, a02 = 0, a03 = 0;
  float a10 = 0, a11 = 0, a12 = 0, a13 = 0;
  int kbeg = wv * 93, kend = kbeg + 93;
  for (int k = kbeg; k < kend; k++) {
    const float* Wr = W + (long)k * D_ + l;
    float w0 = Wr[0], w1 = Wr[64], w2 = Wr[128], w3 = Wr[192];
    float x0 = xr[0][k], x1 = xr[1][k];
    a00 += x0 * w0; a01 += x0 * w1; a02 += x0 * w2; a03 += x0 * w3;
    a10 += x1 * w0; a11 += x1 * w1; a12 += x1 * w2; a13 += x1 * w3;
  }
  part[wv][0][l] = a00; part[wv][0][l + 64] = a01;
  part[wv][0][l + 128] = a02; part[wv][0][l + 192] = a03;
  part[wv][1][l] = a10; part[wv][1][l + 64] = a11;
  part[wv][1][l + 128] = a12; part[wv][1][l + 192] = a13;
  __syncthreads();
  int d = tid;
  #pragma unroll
  for (int r = 0; r < 2; r++) {
    float s = part[0][r][d] + part[1][r][d] + part[2][r][d] + part[3][r][d] + b[d];
    float mean = blkSum256(s, sb) * (1.0f / D_);
    float c = s - mean;
    float var = blkSum256(c * c, sb) * (1.0f / D_);
    float out = c * rsqrtf(var + EPS_);
    int bt = bt0 + r;
    hf[(long)bt * D_ + d] = out;
    hbf[(long)bt * D_ + d] = f2b(out);
    tb2[r][d] = f2b(out);
  }
  __syncthreads();
  // coalesced transposed write: 2 consecutive t per d -> one u32 store
  unsigned tw = (unsigned)tb2[0][d] | ((unsigned)tb2[1][d] << 16);
  *(unsigned*)(hT + ((long)(bt0 >> 9) * D_ + d) * T_ + (bt0 & 511)) = tw;
}

// ---------- qr = rope(relu(h@enc)) ----------
// grid (32, 8, 4)
__global__ __launch_bounds__(256)
void g_enc(const u16* __restrict__ hbf, const u16* __restrict__ enct,
           const unsigned* __restrict__ cs, u16* __restrict__ qr) {
  __shared__ u16 smem[24576];
  int head = blockIdx.z;
  int row0 = blockIdx.y * 128, col0 = blockIdx.x * 128;
  f32x4 acc[4][4];
  gemm128p<0>(hbf, enct + (long)head * NI_ * D_, D_, 0, D_, row0, col0, smem, acc);
  EPILOG_SETUP
  const int tid = threadIdx.x;
  STAGE_FULL(fmaxf(_a, 0.f))
  #pragma unroll
  for (int i = 0; i < 8; i++) {
    int idx = i * 256 + tid;
    int lr = idx >> 4, ch = idx & 15;
    uint4 v = *(const uint4*)(smem + lr * 128 + ((ch ^ ((lr >> 2) & 7)) << 3));
    int gr = row0 + lr;
    int b = gr >> 9, t = gr & 511;
    int gcol = col0 + ch * 8;
    uint4 csv = *(const uint4*)(cs + (long)t * (NI_ / 2) + (gcol >> 1));
    const unsigned* pv = &v.x; const unsigned* pc = &csv.x;
    unsigned o[4];
    #pragma unroll
    for (int j = 0; j < 4; j++) {
      float v0 = b2f((u16)pv[j]), v1 = b2f((u16)(pv[j] >> 16));
      float cc = b2f((u16)pc[j]), ss = b2f((u16)(pc[j] >> 16));
      o[j] = (unsigned)f2b(v0 * cc - v1 * ss) | ((unsigned)f2b(v0 * ss + v1 * cc) << 16);
    }
    long qri = (((long)(b * NH_ + head)) * T_ + t) * NI_ + gcol;
    *(uint4*)(qr + qri) = make_uint4(o[0], o[1], o[2], o[3]);
  }
}

// ---------- scores partials (bf16, SYMMETRIC, split-K 4): upper-tri + mirror ----------
// grid (10, 1, 32)
__global__ __launch_bounds__(256)
void g_scores(const u16* __restrict__ qr, u16* __restrict__ scpb) {
  __shared__ u16 smem[24576];
  int tix = blockIdx.x;
  int by = (tix < 4) ? 0 : (tix < 7) ? 1 : (tix < 9) ? 2 : 3;
  int sub = (by == 0) ? 0 : (by == 1) ? 3 : (by == 2) ? 5 : 6;
  int bx = tix - sub;
  int z2 = blockIdx.z;
  int z = z2 >> 2, ks = z2 & 3;
  const u16* A = qr + (long)z * T_ * NI_;
  int row0 = by * 128, col0 = bx * 128;
  f32x4 acc[4][4];
  if (by == bx)
    gemm128p<1>(A, A, NI_, ks * 1024, ks * 1024 + 1024, row0, col0, smem, acc);
  else
    gemm128p<0>(A, A, NI_, ks * 1024, ks * 1024 + 1024, row0, col0, smem, acc);
  EPILOG_SETUP
  u16* Cb = scpb + (long)(ks * 8 + z) * T_ * T_;
  storeC_full(acc, smem, Cb, T_, row0, col0, wr, wc, lane);
  if (by != bx) {
    // mirrored tile C[s][t] = C[t][s]: stage C^T in LDS, store coalesced rows
    __syncthreads();
    #pragma unroll
    for (int m = 0; m < 4; m++)
      #pragma unroll
      for (int n = 0; n < 4; n++) {
        int lcC = wc + n * 16 + (lane & 15);          // C col -> C^T row
        int lr0 = wr + m * 16 + ((lane >> 4) << 2);   // C row base (aligned 4)
        u16* dstp = smem + lcC * 128 + (lr0 ^ ((lcC & 7) << 3));
        dstp[0] = f2b(acc[m][n][0]);
        dstp[1] = f2b(acc[m][n][1]);
        dstp[2] = f2b(acc[m][n][2]);
        dstp[3] = f2b(acc[m][n][3]);
      }
    __syncthreads();
    const int tid2 = threadIdx.x;
    #pragma unroll
    for (int i = 0; i < 8; i++) {
      int idx = i * 256 + tid2;
      int lrr = idx >> 4, ch = idx & 15;
      uint4 v = *(const uint4*)(smem + lrr * 128 + ((ch ^ (lrr & 7)) << 3));
      *(uint4*)(Cb + (long)(col0 + lrr) * T_ + row0 + ch * 8) = v;
    }
  }
}

// ---------- yKV partials, fused 4-partial score sum in A-staging ----------
// grid (2, 4, 32)
__global__ __launch_bounds__(256)
void g_ykv(const u16* __restrict__ scpb, const u16* __restrict__ hT,
           u16* __restrict__ ykvpb) {
  __shared__ u16 smem[16384];
  u16* Als = smem;
  u16* Bls = smem + 8192;
  int z2 = blockIdx.z;
  int z = z2 >> 2, ks = z2 & 3;
  int b = z >> 2;
  int row0 = blockIdx.y * 128, col0 = blockIdx.x * 128;
  const long SL = (long)8 * T_ * T_;
  const u16* Ab = scpb + (long)z * T_ * T_;
  const u16* Bt = hT + (long)b * D_ * T_;
  const int tid = threadIdx.x;
  const int lane = tid & 63;
  const int wv = tid >> 6;
  const int wr = (wv >> 1) << 6, wc = (wv & 1) << 6;
  const int frow = lane & 15;
  const int kg = lane >> 4;
  const int sw = frow & 7;
  f32x4 acc[4][4];
  #pragma unroll
  for (int m = 0; m < 4; m++)
    #pragma unroll
    for (int n = 0; n < 4; n++) {
      f32x4 zz = {0.f, 0.f, 0.f, 0.f};
      acc[m][n] = zz;
    }
  const int ar = tid >> 1;
  const int ac0 = (tid & 1) << 2;
  for (int k = ks * 128; k < ks * 128 + 128; k += 64) {
    long gb = (long)(row0 + ar) * T_ + k;
    #pragma unroll
    for (int j = 0; j < 4; j++) {
      int jj = ac0 + j;
      long ga = gb + (jj << 3);
      uint4 p0 = *(const uint4*)(Ab + ga);
      uint4 p1 = *(const uint4*)(Ab + SL + ga);
      uint4 p2 = *(const uint4*)(Ab + 2 * SL + ga);
      uint4 p3 = *(const uint4*)(Ab + 3 * SL + ga);
      const unsigned* q0 = &p0.x; const unsigned* q1 = &p1.x;
      const unsigned* q2 = &p2.x; const unsigned* q3 = &p3.x;
      unsigned o[4];
      #pragma unroll
      for (int w = 0; w < 4; w++) {
        float lo = b2f((u16)q0[w]) + b2f((u16)q1[w]) + b2f((u16)q2[w]) + b2f((u16)q3[w]);
        float hi = b2f((u16)(q0[w] >> 16)) + b2f((u16)(q1[w] >> 16)) +
                   b2f((u16)(q2[w] >> 16)) + b2f((u16)(q3[w] >> 16));
        o[w] = (unsigned)f2b(lo) | ((unsigned)f2b(hi) << 16);
      }
      *(uint4*)(Als + ar * 64 + ((jj ^ (ar & 7)) << 3)) = make_uint4(o[0], o[1], o[2], o[3]);
    }
    #pragma unroll
    for (int i = 0; i < 4; i++) {
      int s = tid + (i << 8);
      int r = s >> 3;
      int c = (((s & 7) ^ (r & 7)) << 3);
      gload16(Bt + (long)(col0 + r) * T_ + k + c, Bls + s * 8);
    }
    __syncthreads();
    #pragma unroll
    for (int kk = 0; kk < 2; kk++) {
      const int slot = ((((kk << 2) + kg) ^ sw) << 3);
      bf16x8 af[4], bfv[4];
      #pragma unroll
      for (int m = 0; m < 4; m++)
        af[m] = *(const bf16x8*)(Als + (wr + m * 16 + frow) * 64 + slot);
      #pragma unroll
      for (int n = 0; n < 4; n++)
        bfv[n] = *(const bf16x8*)(Bls + (wc + n * 16 + frow) * 64 + slot);
      __builtin_amdgcn_s_setprio(1);
      #pragma unroll
      for (int m = 0; m < 4; m++)
        #pragma unroll
        for (int n = 0; n < 4; n++)
          acc[m][n] = __builtin_amdgcn_mfma_f32_16x16x32_bf16(af[m], bfv[n], acc[m][n], 0, 0, 0);
      __builtin_amdgcn_s_setprio(0);
    }
    __syncthreads();
  }
  storeC_lds(acc, smem, ykvpb + (long)(ks * 8 + z) * T_ * D_, D_, row0, col0, wr, wc, lane);
}

// ---------- sum 4 yKV partials + LN -> bf16 (wave per row) ----------
__global__ __launch_bounds__(256)
void k_lnykv(const u16* __restrict__ ykvpb, u16* __restrict__ ykvb) {
  int row = blockIdx.x * 4 + (threadIdx.x >> 6);
  int lane = threadIdx.x & 63;
  const long SL = (long)8 * T_ * D_;
  long base = (long)row * D_ + lane * 4;
  float v0 = 0.f, v1 = 0.f, v2 = 0.f, v3 = 0.f;
  #pragma unroll
  for (int p = 0; p < 4; p++) {
    uint2 w = *(const uint2*)(ykvpb + p * SL + base);
    v0 += b2f((u16)w.x); v1 += b2f((u16)(w.x >> 16));
    v2 += b2f((u16)w.y); v3 += b2f((u16)(w.y >> 16));
  }
  float mean = waveSum(v0 + v1 + v2 + v3) * (1.0f / D_);
  float c0 = v0 - mean, c1 = v1 - mean, c2 = v2 - mean, c3 = v3 - mean;
  float var = waveSum(c0 * c0 + c1 * c1 + c2 * c2 + c3 * c3) * (1.0f / D_);
  float rs = rsqrtf(var + EPS_);
  uint2 o;
  o.x = (unsigned)f2b(c0 * rs) | ((unsigned)f2b(c1 * rs) << 16);
  o.y = (unsigned)f2b(c2 * rs) | ((unsigned)f2b(c3 * rs) << 16);
  *(uint2*)(ykvb + base) = o;
}

// ---------- xy = relu(yKV@encv) * relu(inv_rope(qr)) ----------
// grid (32, 4, 8)
__global__ __launch_bounds__(256)
void g_ysp(const u16* __restrict__ ykvb, const u16* __restrict__ encvt,
           const u16* __restrict__ qr, const unsigned* __restrict__ cs,
           u16* __restrict__ xy) {
  __shared__ u16 smem[24576];
  int z = blockIdx.z;
  int b = z >> 2, head = z & 3;
  int row0 = blockIdx.y * 128, col0 = blockIdx.x * 128;
  f32x4 acc[4][4];
  gemm128p<0>(ykvb + (long)z * T_ * D_, encvt + (long)head * NI_ * D_, D_,
              0, D_, row0, col0, smem, acc);
  EPILOG_SETUP
  const int tid = threadIdx.x;
  STAGE_FULL(fmaxf(_a, 0.f))
  #pragma unroll
  for (int i = 0; i < 8; i++) {
    int idx = i * 256 + tid;
    int lr = idx >> 4, ch = idx & 15;
    uint4 v = *(const uint4*)(smem + lr * 128 + ((ch ^ ((lr >> 2) & 7)) << 3));
    int t = row0 + lr;
    int gcol = col0 + ch * 8;
    uint4 qv = *(const uint4*)(qr + ((long)z * T_ + t) * NI_ + gcol);
    uint4 csv = *(const uint4*)(cs + (long)t * (NI_ / 2) + (gcol >> 1));
    const unsigned* pv = &v.x; const unsigned* pq = &qv.x; const unsigned* pc = &csv.x;
    unsigned o[4];
    #pragma unroll
    for (int j = 0; j < 4; j++) {
      float v0 = b2f((u16)pv[j]), v1 = b2f((u16)(pv[j] >> 16));
      float q0 = b2f((u16)pq[j]), q1 = b2f((u16)(pq[j] >> 16));
      float cc = b2f((u16)pc[j]), ss = b2f((u16)(pc[j] >> 16));
      float hs0 = fmaxf(cc * q0 + ss * q1, 0.f);
      float hs1 = fmaxf(cc * q1 - ss * q0, 0.f);
      o[j] = (unsigned)f2b(hs0 * v0) | ((unsigned)f2b(hs1 * v1) << 16);
    }
    long xyi = ((long)b * T_ + t) * (NH_ * NI_) + head * NI_ + gcol;
    *(uint4*)(xy + xyi) = make_uint4(o[0], o[1], o[2], o[3]);
  }
}

// ---------- yMLP partials (bf16): split-K 16 ----------
// grid (2, 8, 16)
__global__ __launch_bounds__(256)
void g_ymlp(const u16* __restrict__ xy, const u16* __restrict__ dect,
            u16* __restrict__ ymlppb) {
  __shared__ u16 smem[24576];
  int ks = blockIdx.z;
  int row0 = blockIdx.y * 128, col0 = blockIdx.x * 128;
  f32x4 acc[4][4];
  gemm128p<0>(xy, dect, NH_ * NI_, ks * 1024, ks * 1024 + 1024, row0, col0, smem, acc);
  EPILOG_SETUP
  storeC_full(acc, smem, ymlppb + (long)ks * (B_ * T_) * D_, D_, row0, col0, wr, wc, lane);
}

// ---------- h = LN(h + LN(sum of 16 partials)) (wave per row) ----------
// LAST=1: final layer, skip hbf/hT (only hf consumed by k_head)
template <int LAST>
__global__ __launch_bounds__(256)
void k_dln(const u16* __restrict__ ymlppb, float* __restrict__ hf,
           u16* __restrict__ hbf, u16* __restrict__ hT) {
  __shared__ u16 tb[4][D_];
  int wv = threadIdx.x >> 6;
  int bt = blockIdx.x * 4 + wv;
  int lane = threadIdx.x & 63;
  const long SL = (long)(B_ * T_) * D_;
  long base = (long)bt * D_ + lane * 4;
  float v0 = 0.f, v1 = 0.f, v2 = 0.f, v3 = 0.f;
  #pragma unroll
  for (int p = 0; p < 16; p++) {
    uint2 w = *(const uint2*)(ymlppb + p * SL + base);
    v0 += b2f((u16)w.x); v1 += b2f((u16)(w.x >> 16));
    v2 += b2f((u16)w.y); v3 += b2f((u16)(w.y >> 16));
  }
  float mean = waveSum(v0 + v1 + v2 + v3) * (1.0f / D_);
  float c0 = v0 - mean, c1 = v1 - mean, c2 = v2 - mean, c3 = v3 - mean;
  float var = waveSum(c0 * c0 + c1 * c1 + c2 * c2 + c3 * c3) * (1.0f / D_);
  float rs = rsqrtf(var + EPS_);
  f32x4 hv = *(const f32x4*)(hf + base);
  float w0 = hv.x + c0 * rs, w1 = hv.y + c1 * rs;
  float w2 = hv.z + c2 * rs, w3 = hv.w + c3 * rs;
  float m2 = waveSum(w0 + w1 + w2 + w3) * (1.0f / D_);
  float e0 = w0 - m2, e1 = w1 - m2, e2 = w2 - m2, e3 = w3 - m2;
  float va2 = waveSum(e0 * e0 + e1 * e1 + e2 * e2 + e3 * e3) * (1.0f / D_);
  float rs2 = rsqrtf(va2 + EPS_);
  float o0 = e0 * rs2, o1 = e1 * rs2, o2 = e2 * rs2, o3 = e3 * rs2;
  f32x4 of = {o0, o1, o2, o3};
  *(f32x4*)(hf + base) = of;
  if (!LAST) {
    uint2 ob;
    ob.x = (unsigned)f2b(o0) | ((unsigned)f2b(o1) << 16);
    ob.y = (unsigned)f2b(o2) | ((unsigned)f2b(o3) << 16);
    *(uint2*)(hbf + base) = ob;
    int d0 = lane * 4;
    tb[wv][d0 + 0] = f2b(o0);
    tb[wv][d0 + 1] = f2b(o1);
    tb[wv][d0 + 2] = f2b(o2);
    tb[wv][d0 + 3] = f2b(o3);
    __syncthreads();
    // coalesced transposed write: 4 consecutive t per d -> one 8B store
    int d = threadIdx.x;
    int bt0 = blockIdx.x * 4;
    uint2 tw;
    tw.x = (unsigned)tb[0][d] | ((unsigned)tb[1][d] << 16);
    tw.y = (unsigned)tb[2][d] | ((unsigned)tb[3][d] << 16);
    *(uint2*)(hT + ((long)(bt0 >> 9) * D_ + d) * T_ + (bt0 & 511)) = tw;
  }
}

// ---------- head: 2 rows/block, K split across 4 waves ----------
__global__ __launch_bounds__(256)
void k_head(const float* __restrict__ h, const float* __restrict__ W,
            const float* __restrict__ bb, float* __restrict__ out) {
  __shared__ float hr[2][D_];
  __shared__ float part[4][2][384];
  int bt0 = blockIdx.x * 2;
  int tid = threadIdx.x;
  int wv = tid >> 6, l = tid & 63;
  for (int i = tid; i < 2 * D_; i += 256)
    hr[i >> 8][i & 255] = h[(long)bt0 * D_ + i];
  __syncthreads();
  float a0[6] = {0.f, 0.f, 0.f, 0.f, 0.f, 0.f};
  float a1[6] = {0.f, 0.f, 0.f, 0.f, 0.f, 0.f};
  int kbeg = wv * 64, kend = kbeg + 64;
  for (int k = kbeg; k < kend; k++) {
    float x0 = hr[0][k], x1 = hr[1][k];
    const float* Wr = W + (long)k * IN_DIM_;
    #pragma unroll
    for (int jj = 0; jj < 6; jj++) {
      int j = l + jj * 64;
      float w = (j < IN_DIM_) ? Wr[j] : 0.f;
      a0[jj] += x0 * w;
      a1[jj] += x1 * w;
    }
  }
  #pragma unroll
  for (int jj = 0; jj < 6; jj++) {
    int j = l + jj * 64;
    part[wv][0][j] = a0[jj];
    part[wv][1][j] = a1[jj];
  }
  __syncthreads();
  #pragma unroll
  for (int pass = 0; pass < 2; pass++) {
    int j = tid + pass * 256;
    if (j < IN_DIM_) {
      float s0 = part[0][0][j] + part[1][0][j] + part[2][0][j] + part[3][0][j] + bb[j];
      float s1 = part[0][1][j] + part[1][1][j] + part[2][1][j] + part[3][1][j] + bb[j];
      out[(long)bt0 * IN_DIM_ + j] = s0;
      out[(long)(bt0 + 1) * IN_DIM_ + j] = s1;
    }
  }
}

extern "C" void kernel_launch(void* const* d_in, const int* in_sizes, int n_in,
                              void* d_out, int out_size, void* d_ws, size_t ws_size,
                              hipStream_t stream) {
  const float* x    = (const float*)d_in[0];
  const float* in_W = (const float*)d_in[1];
  const float* in_b = (const float*)d_in[2];
  const float* enc  = (const float*)d_in[3];
  const float* encv = (const float*)d_in[4];
  const float* dec  = (const float*)d_in[5];
  const float* hW   = (const float*)d_in[6];
  const float* hb   = (const float*)d_in[7];
  float* out = (float*)d_out;

  char* p = (char*)d_ws;
  auto alloc = [&](size_t bytes) { char* r = p; p += (bytes + 255) & ~(size_t)255; return r; };
  unsigned* cs   = (unsigned*)alloc((size_t)T_ * (NI_ / 2) * 4);     // 4 MB
  float* hf      = (float*)alloc((size_t)B_ * T_ * D_ * 4);          // 1 MB
  u16*   hbf     = (u16*)  alloc((size_t)B_ * T_ * D_ * 2);
  u16*   hT      = (u16*)  alloc((size_t)B_ * D_ * T_ * 2);
  u16*   enct    = (u16*)  alloc((size_t)NH_ * D_ * NI_ * 2);        // 8 MB
  u16*   encvt   = (u16*)  alloc((size_t)NH_ * D_ * NI_ * 2);        // 8 MB
  u16*   dect    = (u16*)  alloc((size_t)NH_ * NI_ * D_ * 2);        // 8 MB
  u16*   qr      = (u16*)  alloc((size_t)B_ * NH_ * T_ * NI_ * 2);   // 32 MB
  u16*   xy      = (u16*)  alloc((size_t)B_ * T_ * NH_ * NI_ * 2);   // 32 MB
  u16*   scpb    = (u16*)  alloc((size_t)4 * 8 * T_ * T_ * 2);       // 16 MB
  u16*   ykvpb   = (u16*)  alloc((size_t)4 * 8 * T_ * D_ * 2);       // 8 MB
  u16*   ykvb    = (u16*)  alloc((size_t)8 * T_ * D_ * 2);           // 2 MB
  u16*   ymlppb  = (u16*)  alloc((size_t)16 * B_ * T_ * D_ * 2);     // 8 MB

  k_pre<<<dim3(7168), dim3(256), 0, stream>>>(enc, encv, dec, enct, encvt, dect, cs);
  k_input<<<dim3(B_ * T_ / 2), dim3(256), 0, stream>>>(x, in_W, in_b, hf, hbf, hT);

  for (int l = 0; l < NL_; l++) {
    g_enc<<<dim3(32, 8, 4), dim3(256), 0, stream>>>(hbf, enct, cs, qr);
    g_scores<<<dim3(10, 1, 32), dim3(256), 0, stream>>>(qr, scpb);
    g_ykv<<<dim3(2, 4, 32), dim3(256), 0, stream>>>(scpb, hT, ykvpb);
    k_lnykv<<<dim3(1024), dim3(256), 0, stream>>>(ykvpb, ykvb);
    g_ysp<<<dim3(32, 4, 8), dim3(256), 0, stream>>>(ykvb, encvt, qr, cs, xy);
    g_ymlp<<<dim3(2, 8, 16), dim3(256), 0, stream>>>(xy, dect, ymlppb);
    if (l == NL_ - 1)
      k_dln<1><<<dim3(256), dim3(256), 0, stream>>>(ymlppb, hf, hbf, hT);
    else
      k_dln<0><<<dim3(256), dim3(256), 0, stream>>>(ymlppb, hf, hbf, hT);
  }

  k_head<<<dim3(B_ * T_ / 2), dim3(256), 0, stream>>>(hf, hW, hb, out);
}